// Round 10
// baseline (413.258 us; speedup 1.0000x reference)
//
#include <hip/hip_runtime.h>
#include <hip/hip_bf16.h>
#include <math.h>

#define BB 16
#define CC 256
#define C2 128
#define NN 2048

typedef __attribute__((ext_vector_type(8))) _Float16 f16x8;
typedef __attribute__((ext_vector_type(8))) short bf16x8;
typedef __attribute__((ext_vector_type(16))) float f32x16;
typedef unsigned short u16;

// ---- workspace layout (float offsets) ----
#define OFF_X2    ((size_t)0)           // x2 fp32 [B][C][N]
#define OFF_U16   ((size_t)16777216)    // u16 region 1: XQT | XKT | XV
#define UOFF_XQT  ((size_t)0)           // fp16 [B][N][C2]
#define UOFF_XKT  ((size_t)4194304)     // fp16 [B][N][C2]
#define UOFF_XV   ((size_t)8388608)     // bf16 [B][C][N]
#define OFF_RMAX0 ((size_t)25165824)
#define OFF_RSUM0 ((size_t)25198592)
#define OFF_RMAX1 ((size_t)25231360)
#define OFF_T16   ((size_t)25264128)    // u16 region 2: dT fp16 [B][N][CC]
#define OFF_W16   ((size_t)29458432)    // u16: Wq16|Wk16|Wv16|Wt16
#define OFF_RSUM1 ((size_t)29523968)
#define WOFF_WQ   ((size_t)0)
#define WOFF_WK   ((size_t)16384)
#define WOFF_WV   ((size_t)32768)
#define WOFF_WT   ((size_t)65536)

__device__ __forceinline__ u16 f2h(float f) {
    union { _Float16 h; u16 u; } v; v.h = (_Float16)f;
    return v.u;
}
__device__ __forceinline__ u16 f2bf(float f) {
    union { float f; unsigned u; } v; v.f = f;
    return (u16)((v.u + 0x7fffu + ((v.u >> 16) & 1u)) >> 16);
}

// ---------------- prep: weights -> fp16 ----------------
__global__ __launch_bounds__(256) void prep_w(
    const float* __restrict__ Wq, const float* __restrict__ Wk,
    const float* __restrict__ Wv, const float* __restrict__ Wt,
    u16* __restrict__ w16)
{
    int i = blockIdx.x * 256 + threadIdx.x;   // 131072 total
    float v;
    if (i < 16384)      v = Wq[i];
    else if (i < 32768) v = Wk[i - 16384];
    else if (i < 65536) v = Wv[i - 32768];
    else                v = Wt[i - 65536];
    w16[i] = f2h(v);
}

// ---------------- fused projection ----------------
__global__ __launch_bounds__(256, 2) void proj_fused(
    const float* __restrict__ in, const u16* __restrict__ wqk,
    const u16* __restrict__ wv, const float* __restrict__ bias,
    u16* __restrict__ outT, u16* __restrict__ outv_bf,
    float* __restrict__ outv_f32)
{
    __shared__ u16 t_s[64 * 136];     // [n][c] fp16
    int tid = threadIdx.x, lane = tid & 63, wave = tid >> 6;
    int b = blockIdx.z, n0 = blockIdx.x * 64;
    {
        int r = tid >> 2;             // c within 64-half
        int nc = (tid & 3) * 16;      // n-chunk
        #pragma unroll
        for (int h = 0; h < 2; ++h) {
            const float4* ip4 = (const float4*)(in + ((size_t)b * C2 + h * 64 + r) * NN + n0 + nc);
            #pragma unroll
            for (int jj = 0; jj < 4; ++jj) {
                float4 v = ip4[jj];
                int nbase = nc + jj * 4;
                t_s[(nbase + 0) * 136 + h * 64 + r] = f2h(v.x);
                t_s[(nbase + 1) * 136 + h * 64 + r] = f2h(v.y);
                t_s[(nbase + 2) * 136 + h * 64 + r] = f2h(v.z);
                t_s[(nbase + 3) * 136 + h * 64 + r] = f2h(v.w);
            }
        }
    }
    __syncthreads();
    int nsub = wave & 1, g = wave >> 1;   // g in {0,1}
    int lrow = lane & 31, lk8 = (lane >> 5) * 8;
    const u16* brow = &t_s[(nsub * 32 + lrow) * 136 + lk8];
    f32x16 aq0, aq1, av0, av1, av2, av3;
    #pragma unroll
    for (int r = 0; r < 16; ++r)
        { aq0[r]=0.f; aq1[r]=0.f; av0[r]=0.f; av1[r]=0.f; av2[r]=0.f; av3[r]=0.f; }
    const u16* wq0 = wqk + (size_t)(g * 64 + lrow) * C2 + lk8;
    const u16* wq1 = wqk + (size_t)(g * 64 + 32 + lrow) * C2 + lk8;
    const u16* wv0 = wv + (size_t)(g * 128 + lrow) * C2 + lk8;
    const u16* wv1 = wv + (size_t)(g * 128 + 32 + lrow) * C2 + lk8;
    const u16* wv2 = wv + (size_t)(g * 128 + 64 + lrow) * C2 + lk8;
    const u16* wv3 = wv + (size_t)(g * 128 + 96 + lrow) * C2 + lk8;
    #pragma unroll
    for (int kk = 0; kk < 8; ++kk) {
        f16x8 bf = *(const f16x8*)&brow[kk * 16];
        f16x8 q0 = *(const f16x8*)&wq0[kk * 16];
        f16x8 q1 = *(const f16x8*)&wq1[kk * 16];
        aq0 = __builtin_amdgcn_mfma_f32_32x32x16_f16(bf, q0, aq0, 0, 0, 0);
        aq1 = __builtin_amdgcn_mfma_f32_32x32x16_f16(bf, q1, aq1, 0, 0, 0);
        f16x8 v0 = *(const f16x8*)&wv0[kk * 16];
        f16x8 v1 = *(const f16x8*)&wv1[kk * 16];
        f16x8 v2 = *(const f16x8*)&wv2[kk * 16];
        f16x8 v3 = *(const f16x8*)&wv3[kk * 16];
        av0 = __builtin_amdgcn_mfma_f32_32x32x16_f16(v0, bf, av0, 0, 0, 0);
        av1 = __builtin_amdgcn_mfma_f32_32x32x16_f16(v1, bf, av1, 0, 0, 0);
        av2 = __builtin_amdgcn_mfma_f32_32x32x16_f16(v2, bf, av2, 0, 0, 0);
        av3 = __builtin_amdgcn_mfma_f32_32x32x16_f16(v3, bf, av3, 0, 0, 0);
    }
    #pragma unroll
    for (int r = 0; r < 16; ++r) {
        int ro = (r & 3) + 8 * (r >> 2) + 4 * (lane >> 5);
        size_t row = (size_t)b * NN + n0 + nsub * 32 + ro;
        outT[row * C2 + g * 64 + lrow]      = f2h(aq0[r]);
        outT[row * C2 + g * 64 + 32 + lrow] = f2h(aq1[r]);
    }
    int n = n0 + nsub * 32 + lrow;
    #pragma unroll
    for (int r = 0; r < 16; ++r) {
        int ro = (r & 3) + 8 * (r >> 2) + 4 * (lane >> 5);
        int c0r = g * 128 + ro;
        float w0 = av0[r] + bias[c0r];
        float w1 = av1[r] + bias[c0r + 32];
        float w2 = av2[r] + bias[c0r + 64];
        float w3 = av3[r] + bias[c0r + 96];
        if (outv_bf) {
            outv_bf[((size_t)b * CC + c0r) * NN + n]      = f2bf(w0);
            outv_bf[((size_t)b * CC + c0r + 32) * NN + n] = f2bf(w1);
            outv_bf[((size_t)b * CC + c0r + 64) * NN + n] = f2bf(w2);
            outv_bf[((size_t)b * CC + c0r + 96) * NN + n] = f2bf(w3);
        } else {
            outv_f32[((size_t)b * CC + c0r) * NN + n]      = w0;
            outv_f32[((size_t)b * CC + c0r + 32) * NN + n] = w1;
            outv_f32[((size_t)b * CC + c0r + 64) * NN + n] = w2;
            outv_f32[((size_t)b * CC + c0r + 96) * NN + n] = w3;
        }
    }
}

// ---------------- Pass 1: row stats — batched fragment loads, zero in-loop barriers ----------------
__global__ __launch_bounds__(256, 4) void rowstats_mfma(
    const u16* __restrict__ xqT, const u16* __restrict__ xkT,
    float* __restrict__ rmax0, float* __restrict__ rsum0,
    float* __restrict__ rmax1, float* __restrict__ rsum1)
{
    __shared__ u16 xq_s[64 * 136];
    __shared__ float Mp[4][32];
    __shared__ float Sp[4][32];
    const int tid  = threadIdx.x;
    int flat = blockIdx.x + gridDim.x * blockIdx.y;   // 1024
    int xcd = flat & 7, rank = flat >> 3;             // rank in [0,128)
    const int b    = xcd * 2 + (rank >> 6);
    const int sub  = rank & 63;
    const int n0   = (sub >> 1) * 64;
    const int half = sub & 1;
    const int lane = tid & 63;
    const int wave = tid >> 6;
    const u16* xqb = xqT + (size_t)b * NN * C2;
    const u16* xkb = xkT + (size_t)b * NN * C2;

    for (int i = tid; i < 64 * 16; i += 256) {
        int r = i >> 4, c8 = i & 15;
        *(uint4*)&xq_s[r * 136 + c8 * 8] =
            *(const uint4*)&xqb[(size_t)(n0 + r) * C2 + c8 * 8];
    }
    __syncthreads();
    const int msub = wave >> 1, nsub = wave & 1;
    const int lrow = lane & 31;
    const int lk8  = (lane >> 5) * 8;
    const u16* brow = &xq_s[(nsub * 32 + lrow) * 136 + lk8];
    float runM = -1e30f, runS = 0.f;
    const int mbeg = half * 1024;

    for (int m0 = mbeg; m0 < mbeg + 1024; m0 += 64) {
        const u16* ar = xkb + (size_t)(m0 + msub * 32 + lrow) * C2 + lk8;
        // batch-issue all 8 A fragments (pipelined vmcnt waits)
        f16x8 k0 = *(const f16x8*)&ar[0];
        f16x8 k1 = *(const f16x8*)&ar[16];
        f16x8 k2 = *(const f16x8*)&ar[32];
        f16x8 k3 = *(const f16x8*)&ar[48];
        f16x8 k4 = *(const f16x8*)&ar[64];
        f16x8 k5 = *(const f16x8*)&ar[80];
        f16x8 k6 = *(const f16x8*)&ar[96];
        f16x8 k7 = *(const f16x8*)&ar[112];
        f32x16 e;
        #pragma unroll
        for (int r = 0; r < 16; ++r) e[r] = 0.f;
        e = __builtin_amdgcn_mfma_f32_32x32x16_f16(k0, *(const f16x8*)&brow[0],   e, 0, 0, 0);
        e = __builtin_amdgcn_mfma_f32_32x32x16_f16(k1, *(const f16x8*)&brow[16],  e, 0, 0, 0);
        e = __builtin_amdgcn_mfma_f32_32x32x16_f16(k2, *(const f16x8*)&brow[32],  e, 0, 0, 0);
        e = __builtin_amdgcn_mfma_f32_32x32x16_f16(k3, *(const f16x8*)&brow[48],  e, 0, 0, 0);
        e = __builtin_amdgcn_mfma_f32_32x32x16_f16(k4, *(const f16x8*)&brow[64],  e, 0, 0, 0);
        e = __builtin_amdgcn_mfma_f32_32x32x16_f16(k5, *(const f16x8*)&brow[80],  e, 0, 0, 0);
        e = __builtin_amdgcn_mfma_f32_32x32x16_f16(k6, *(const f16x8*)&brow[96],  e, 0, 0, 0);
        e = __builtin_amdgcn_mfma_f32_32x32x16_f16(k7, *(const f16x8*)&brow[112], e, 0, 0, 0);
        float tm = e[0];
        #pragma unroll
        for (int r = 1; r < 16; ++r) tm = fmaxf(tm, e[r]);
        float newM = fmaxf(runM, tm);
        float sc = __expf(runM - newM);
        float ts = 0.f;
        #pragma unroll
        for (int r = 0; r < 16; ++r) ts += __expf(e[r] - newM);
        runS = runS * sc + ts;
        runM = newM;
    }
    float oM = __shfl_xor(runM, 32, 64);
    float oS = __shfl_xor(runS, 32, 64);
    float M2 = fmaxf(runM, oM);
    float S2 = runS * __expf(runM - M2) + oS * __expf(oM - M2);
    if (lane < 32) { Mp[wave][lane] = M2; Sp[wave][lane] = S2; }
    __syncthreads();
    if (tid < 64) {
        int ns = tid >> 5, li = tid & 31;
        float Ma = Mp[ns][li], Mb = Mp[ns + 2][li];
        float Mf = fmaxf(Ma, Mb);
        float Sf = Sp[ns][li] * __expf(Ma - Mf) + Sp[ns + 2][li] * __expf(Mb - Mf);
        float* rm = half ? rmax1 : rmax0;
        float* rs = half ? rsum1 : rsum0;
        rm[(size_t)b * NN + n0 + tid] = Mf;
        rs[(size_t)b * NN + n0 + tid] = Sf;
    }
}

// ---------------- Pass 2: PV + fused dcalc — batched fragment loads ----------------
__global__ __launch_bounds__(256, 4) void pv_mfma(
    const u16* __restrict__ xqT, const u16* __restrict__ xkT,
    const u16* __restrict__ xv,
    const float* __restrict__ rmax0, const float* __restrict__ rsum0,
    const float* __restrict__ rmax1, const float* __restrict__ rsum1,
    const float* __restrict__ x2, u16* __restrict__ dT)
{
    __shared__ u16 smem[9280];       // loop: xk_s[32*136] | p_s[32*136]; epi: dts[32*264] + s_part + sinv
    u16* xk_s = smem;                // [32][136] fp16
    u16* p_s  = smem + 4352;         // [32][136] bf16  ([m][n], n-step 128)
    const int tid  = threadIdx.x;
    int flat = blockIdx.x + gridDim.x * blockIdx.y;   // 1024
    int xcd = flat & 7, rank = flat >> 3;
    const int b  = xcd * 2 + (rank >> 6);
    const int m0 = (rank & 63) * 32;
    const int lane = tid & 63;
    const int wave = tid >> 6;
    const u16* xqb = xqT + (size_t)b * NN * C2;
    const u16* xkb = xkT + (size_t)b * NN * C2;
    const u16* xvb = xv + (size_t)b * CC * NN;

    for (int i = tid; i < 32 * 16; i += 256) {
        int r = i >> 4, c8 = i & 15;
        *(uint4*)&xk_s[r * 136 + c8 * 8] =
            *(const uint4*)&xkb[(size_t)(m0 + r) * C2 + c8 * 8];
    }
    f32x16 acc0, acc1;
    #pragma unroll
    for (int r = 0; r < 16; ++r) { acc0[r] = 0.f; acc1[r] = 0.f; }
    float s_reg = 0.f;
    const int lrow  = lane & 31;
    const int lk8   = (lane >> 5) * 8;
    const int cbase = wave * 64;
    const int nl    = wave * 32 + lrow;
    const int mbase = 4 * (lane >> 5);
    const int cs_m  = tid & 31, cs_ch = tid >> 5;
    __syncthreads();   // xk_s ready

    for (int n0 = 0; n0 < NN; n0 += 128) {
        // ---- batch-issue energy B frags + row stats ----
        const u16* bg = xqb + (size_t)(n0 + nl) * C2 + lk8;
        f16x8 q0 = *(const f16x8*)&bg[0];
        f16x8 q1 = *(const f16x8*)&bg[16];
        f16x8 q2 = *(const f16x8*)&bg[32];
        f16x8 q3 = *(const f16x8*)&bg[48];
        f16x8 q4 = *(const f16x8*)&bg[64];
        f16x8 q5 = *(const f16x8*)&bg[80];
        f16x8 q6 = *(const f16x8*)&bg[96];
        f16x8 q7 = *(const f16x8*)&bg[112];
        size_t sidx = (size_t)b * NN + n0 + nl;
        float M0 = rmax0[sidx], S0 = rsum0[sidx];
        float M1 = rmax1[sidx], S1 = rsum1[sidx];
        // ---- energy MFMAs (A from LDS) ----
        const u16* arow = &xk_s[lrow * 136 + lk8];
        f32x16 e;
        #pragma unroll
        for (int r = 0; r < 16; ++r) e[r] = 0.f;
        e = __builtin_amdgcn_mfma_f32_32x32x16_f16(*(const f16x8*)&arow[0],   q0, e, 0, 0, 0);
        e = __builtin_amdgcn_mfma_f32_32x32x16_f16(*(const f16x8*)&arow[16],  q1, e, 0, 0, 0);
        e = __builtin_amdgcn_mfma_f32_32x32x16_f16(*(const f16x8*)&arow[32],  q2, e, 0, 0, 0);
        e = __builtin_amdgcn_mfma_f32_32x32x16_f16(*(const f16x8*)&arow[48],  q3, e, 0, 0, 0);
        e = __builtin_amdgcn_mfma_f32_32x32x16_f16(*(const f16x8*)&arow[64],  q4, e, 0, 0, 0);
        e = __builtin_amdgcn_mfma_f32_32x32x16_f16(*(const f16x8*)&arow[80],  q5, e, 0, 0, 0);
        e = __builtin_amdgcn_mfma_f32_32x32x16_f16(*(const f16x8*)&arow[96],  q6, e, 0, 0, 0);
        e = __builtin_amdgcn_mfma_f32_32x32x16_f16(*(const f16x8*)&arow[112], q7, e, 0, 0, 0);
        {
            float Mn = fmaxf(M0, M1);
            float Si = 1.f / (S0 * __expf(M0 - Mn) + S1 * __expf(M1 - Mn));
            #pragma unroll
            for (int r = 0; r < 16; ++r) {
                int ml = mbase + (r & 3) + 8 * (r >> 2);
                float p = __expf(e[r] - Mn) * Si;
                p_s[ml * 136 + nl] = f2bf(p);
            }
        }
        __syncthreads();   // A: p_s ready
        // ---- PV half 1: batch-issue 8 A frags, colsum while they fly ----
        const u16* a0g = xvb + (size_t)(cbase + lrow) * NN + n0 + lk8;
        const u16* a1g = xvb + (size_t)(cbase + 32 + lrow) * NN + n0 + lk8;
        bf16x8 va00 = *(const bf16x8*)&a0g[0];
        bf16x8 va01 = *(const bf16x8*)&a0g[16];
        bf16x8 va02 = *(const bf16x8*)&a0g[32];
        bf16x8 va03 = *(const bf16x8*)&a0g[48];
        bf16x8 va10 = *(const bf16x8*)&a1g[0];
        bf16x8 va11 = *(const bf16x8*)&a1g[16];
        bf16x8 va12 = *(const bf16x8*)&a1g[32];
        bf16x8 va13 = *(const bf16x8*)&a1g[48];
        // colsum partial (LDS reads overlap the global loads above)
        {
            const uint4* pr = (const uint4*)&p_s[cs_m * 136 + cs_ch * 16];
            uint4 v0 = pr[0], v1 = pr[1];
            unsigned wsv[8] = {v0.x, v0.y, v0.z, v0.w, v1.x, v1.y, v1.z, v1.w};
            float ss = 0.f;
            #pragma unroll
            for (int j = 0; j < 8; ++j) {
                union { unsigned u; float f; } lo, hi;
                lo.u = wsv[j] << 16;
                hi.u = wsv[j] & 0xffff0000u;
                ss += lo.f + hi.f;
            }
            s_reg += ss;
        }
        const u16* br = &p_s[lrow * 136 + lk8];
        acc0 = __builtin_amdgcn_mfma_f32_32x32x16_bf16(va00, *(const bf16x8*)&br[0],  acc0, 0, 0, 0);
        acc1 = __builtin_amdgcn_mfma_f32_32x32x16_bf16(va10, *(const bf16x8*)&br[0],  acc1, 0, 0, 0);
        acc0 = __builtin_amdgcn_mfma_f32_32x32x16_bf16(va01, *(const bf16x8*)&br[16], acc0, 0, 0, 0);
        acc1 = __builtin_amdgcn_mfma_f32_32x32x16_bf16(va11, *(const bf16x8*)&br[16], acc1, 0, 0, 0);
        acc0 = __builtin_amdgcn_mfma_f32_32x32x16_bf16(va02, *(const bf16x8*)&br[32], acc0, 0, 0, 0);
        acc1 = __builtin_amdgcn_mfma_f32_32x32x16_bf16(va12, *(const bf16x8*)&br[32], acc1, 0, 0, 0);
        acc0 = __builtin_amdgcn_mfma_f32_32x32x16_bf16(va03, *(const bf16x8*)&br[48], acc0, 0, 0, 0);
        acc1 = __builtin_amdgcn_mfma_f32_32x32x16_bf16(va13, *(const bf16x8*)&br[48], acc1, 0, 0, 0);
        // ---- PV half 2 ----
        bf16x8 vb00 = *(const bf16x8*)&a0g[64];
        bf16x8 vb01 = *(const bf16x8*)&a0g[80];
        bf16x8 vb02 = *(const bf16x8*)&a0g[96];
        bf16x8 vb03 = *(const bf16x8*)&a0g[112];
        bf16x8 vb10 = *(const bf16x8*)&a1g[64];
        bf16x8 vb11 = *(const bf16x8*)&a1g[80];
        bf16x8 vb12 = *(const bf16x8*)&a1g[96];
        bf16x8 vb13 = *(const bf16x8*)&a1g[112];
        acc0 = __builtin_amdgcn_mfma_f32_32x32x16_bf16(vb00, *(const bf16x8*)&br[64],  acc0, 0, 0, 0);
        acc1 = __builtin_amdgcn_mfma_f32_32x32x16_bf16(vb10, *(const bf16x8*)&br[64],  acc1, 0, 0, 0);
        acc0 = __builtin_amdgcn_mfma_f32_32x32x16_bf16(vb01, *(const bf16x8*)&br[80],  acc0, 0, 0, 0);
        acc1 = __builtin_amdgcn_mfma_f32_32x32x16_bf16(vb11, *(const bf16x8*)&br[80],  acc1, 0, 0, 0);
        acc0 = __builtin_amdgcn_mfma_f32_32x32x16_bf16(vb02, *(const bf16x8*)&br[96],  acc0, 0, 0, 0);
        acc1 = __builtin_amdgcn_mfma_f32_32x32x16_bf16(vb12, *(const bf16x8*)&br[96],  acc1, 0, 0, 0);
        acc0 = __builtin_amdgcn_mfma_f32_32x32x16_bf16(vb03, *(const bf16x8*)&br[112], acc0, 0, 0, 0);
        acc1 = __builtin_amdgcn_mfma_f32_32x32x16_bf16(vb13, *(const bf16x8*)&br[112], acc1, 0, 0, 0);
        __syncthreads();   // B: p_s reads done before next iter's writes
    }
    // ---- fused dcalc epilogue ----
    float* s_part = (float*)&smem[8704];    // [32][8]
    s_part[cs_m * 8 + cs_ch] = s_reg;
    __syncthreads();
    float* sinv = (float*)&smem[9216];      // [32]
    if (tid < 32) {
        float ss = 0.f;
        #pragma unroll
        for (int j = 0; j < 8; ++j) ss += s_part[tid * 8 + j];
        sinv[tid] = 1.f / (1e-9f + ss);
    }
    __syncthreads();
    u16* dts = smem;                         // [32][264], overlaps dead xk_s/p_s
    const float* x2b = x2 + (size_t)b * CC * NN;
    float si = sinv[lrow];
    #pragma unroll
    for (int r = 0; r < 16; ++r) {
        int ro = (r & 3) + 8 * (r >> 2) + 4 * (lane >> 5);
        int c0r = cbase + ro, c1r = cbase + 32 + ro;
        float d0 = x2b[(size_t)c0r * NN + m0 + lrow] - acc0[r] * si;
        float d1 = x2b[(size_t)c1r * NN + m0 + lrow] - acc1[r] * si;
        dts[lrow * 264 + c0r] = f2h(d0);
        dts[lrow * 264 + c1r] = f2h(d1);
    }
    __syncthreads();
    u16* op = dT + ((size_t)b * NN + m0) * CC;
    for (int i = tid; i < 32 * 32; i += 256) {
        int r = i >> 5, c8 = i & 31;
        *(uint4*)&op[(size_t)r * CC + c8 * 8] = *(uint4*)&dts[r * 264 + c8 * 8];
    }
}

// ---------------- final (MFMA): out = relu(BN(Wt·d + bt)) + x2 ----------------
__global__ __launch_bounds__(256) void final_mfma(
    const u16* __restrict__ dT, const u16* __restrict__ wt16,
    const float* __restrict__ bt, const float* __restrict__ gamma,
    const float* __restrict__ beta, const float* __restrict__ rmean,
    const float* __restrict__ rvar, const float* __restrict__ x2,
    float* __restrict__ out)
{
    __shared__ u16 b_s[64 * 264];
    __shared__ float inv_s[128], add_s[128];
    int tid = threadIdx.x, lane = tid & 63, wave = tid >> 6;
    int n0 = blockIdx.x * 64, o0 = blockIdx.y * 128, b = blockIdx.z;
    for (int i = tid; i < 64 * 32; i += 256) {
        int r = i >> 5, c8 = i & 31;
        *(uint4*)&b_s[r * 264 + c8 * 8] =
            *(const uint4*)&dT[((size_t)b * NN + n0 + r) * CC + c8 * 8];
    }
    if (tid < 128) {
        int o = o0 + tid;
        float iv = gamma[o] * rsqrtf(rvar[o] + 1e-5f);
        inv_s[tid] = iv;
        add_s[tid] = bt[o] * iv + beta[o] - rmean[o] * iv;
    }
    __syncthreads();
    int oh = wave >> 1, nsub = wave & 1;
    int lrow = lane & 31, lk8 = (lane >> 5) * 8;
    f32x16 acc0, acc1;
    #pragma unroll
    for (int r = 0; r < 16; ++r) { acc0[r] = 0.f; acc1[r] = 0.f; }
    const u16* brow = &b_s[(nsub * 32 + lrow) * 264 + lk8];
    const u16* a0p = wt16 + (size_t)(o0 + oh * 64 + lrow) * CC + lk8;
    const u16* a1p = wt16 + (size_t)(o0 + oh * 64 + 32 + lrow) * CC + lk8;
    #pragma unroll
    for (int kk = 0; kk < 16; ++kk) {
        f16x8 bb = *(const f16x8*)&brow[kk * 16];
        f16x8 a0 = *(const f16x8*)&a0p[kk * 16];
        f16x8 a1 = *(const f16x8*)&a1p[kk * 16];
        acc0 = __builtin_amdgcn_mfma_f32_32x32x16_f16(a0, bb, acc0, 0, 0, 0);
        acc1 = __builtin_amdgcn_mfma_f32_32x32x16_f16(a1, bb, acc1, 0, 0, 0);
    }
    int n = n0 + nsub * 32 + (lane & 31);
    #pragma unroll
    for (int r = 0; r < 16; ++r) {
        int ro = (r & 3) + 8 * (r >> 2) + 4 * (lane >> 5);
        int ol0 = oh * 64 + ro, ol1 = ol0 + 32;
        float t0 = acc0[r] * inv_s[ol0] + add_s[ol0];
        float t1 = acc1[r] * inv_s[ol1] + add_s[ol1];
        size_t i0 = ((size_t)b * CC + o0 + ol0) * NN + n;
        size_t i1 = ((size_t)b * CC + o0 + ol1) * NN + n;
        out[i0] = fmaxf(t0, 0.f) + x2[i0];
        out[i1] = fmaxf(t1, 0.f) + x2[i1];
    }
}

extern "C" void kernel_launch(void* const* d_in, const int* in_sizes, int n_in,
                              void* d_out, int out_size, void* d_ws, size_t ws_size,
                              hipStream_t stream)
{
    const float* q     = (const float*)d_in[0];
    const float* x     = (const float*)d_in[1];
    const float* Wq    = (const float*)d_in[2];
    const float* Wk    = (const float*)d_in[3];
    const float* Wv    = (const float*)d_in[4];
    const float* bv    = (const float*)d_in[5];
    const float* Wt    = (const float*)d_in[6];
    const float* bt    = (const float*)d_in[7];
    const float* gamma = (const float*)d_in[8];
    const float* beta  = (const float*)d_in[9];
    const float* rmean = (const float*)d_in[10];
    const float* rvar  = (const float*)d_in[11];
    float* out = (float*)d_out;
    float* ws  = (float*)d_ws;

    float* x2    = ws + OFF_X2;
    u16*   u1    = (u16*)(ws + OFF_U16);
    u16*   xqT   = u1 + UOFF_XQT;
    u16*   xkT   = u1 + UOFF_XKT;
    u16*   xv    = u1 + UOFF_XV;
    float* rmax0 = ws + OFF_RMAX0;
    float* rsum0 = ws + OFF_RSUM0;
    float* rmax1 = ws + OFF_RMAX1;
    float* rsum1 = ws + OFF_RSUM1;
    u16*   dT    = (u16*)(ws + OFF_T16);
    u16*   w16   = (u16*)(ws + OFF_W16);

    dim3 blk(256);
    prep_w<<<dim3(512), blk, 0, stream>>>(Wq, Wk, Wv, Wt, w16);
    proj_fused<<<dim3(NN/64, 1, BB), blk, 0, stream>>>(
        q, w16 + WOFF_WQ, w16 + WOFF_WV, bv, xqT, xv, nullptr);
    proj_fused<<<dim3(NN/64, 1, BB), blk, 0, stream>>>(
        x, w16 + WOFF_WK, w16 + WOFF_WV, bv, xkT, nullptr, x2);
    rowstats_mfma<<<dim3(64, 16), blk, 0, stream>>>(xqT, xkT, rmax0, rsum0, rmax1, rsum1);
    pv_mfma<<<dim3(64, 16), blk, 0, stream>>>(xqT, xkT, xv, rmax0, rsum0, rmax1, rsum1,
                                              x2, dT);
    final_mfma<<<dim3(NN/64, 2, BB), blk, 0, stream>>>(dT, w16 + WOFF_WT, bt, gamma,
                                                       beta, rmean, rvar, x2, out);
}

// Round 11
// 335.620 us; speedup vs baseline: 1.2313x; 1.2313x over previous
//
#include <hip/hip_runtime.h>
#include <hip/hip_bf16.h>
#include <math.h>

#define BB 16
#define CC 256
#define C2 128
#define NN 2048

typedef __attribute__((ext_vector_type(8))) _Float16 f16x8;
typedef __attribute__((ext_vector_type(8))) short bf16x8;
typedef __attribute__((ext_vector_type(16))) float f32x16;
typedef unsigned short u16;

// ---- workspace layout (float offsets) ----
#define OFF_X2   ((size_t)0)           // x2 fp32 [B][C][N]
#define OFF_U16  ((size_t)16777216)    // u16 region 1: XQT | XKT | XV
#define UOFF_XQT ((size_t)0)           // fp16 [B][N][C2]
#define UOFF_XKT ((size_t)4194304)     // fp16 [B][N][C2]
#define UOFF_XV  ((size_t)8388608)     // bf16 [B][C][N]
#define OFF_RMAX ((size_t)25165824)
#define OFF_RSUM ((size_t)25198592)
#define OFF_T16  ((size_t)25264128)    // u16 region 2: dT fp16 [B][N][CC]
#define OFF_W16  ((size_t)29458432)    // u16: Wq16|Wk16|Wv16|Wt16
#define WOFF_WQ  ((size_t)0)
#define WOFF_WK  ((size_t)16384)
#define WOFF_WV  ((size_t)32768)
#define WOFF_WT  ((size_t)65536)

__device__ __forceinline__ u16 f2h(float f) {
    union { _Float16 h; u16 u; } v; v.h = (_Float16)f;
    return v.u;
}
__device__ __forceinline__ u16 f2bf(float f) {
    union { float f; unsigned u; } v; v.f = f;
    return (u16)((v.u + 0x7fffu + ((v.u >> 16) & 1u)) >> 16);
}
__device__ __forceinline__ float bf2f(u16 h) {
    union { unsigned u; float f; } v; v.u = ((unsigned)h) << 16;
    return v.f;
}

// ---------------- prep: weights -> fp16 ----------------
__global__ __launch_bounds__(256) void prep_w(
    const float* __restrict__ Wq, const float* __restrict__ Wk,
    const float* __restrict__ Wv, const float* __restrict__ Wt,
    u16* __restrict__ w16)
{
    int i = blockIdx.x * 256 + threadIdx.x;   // 131072 total
    float v;
    if (i < 16384)      v = Wq[i];
    else if (i < 32768) v = Wk[i - 16384];
    else if (i < 65536) v = Wv[i - 32768];
    else                v = Wt[i - 65536];
    w16[i] = f2h(v);
}

// ---------------- fused projection (both inputs in ONE launch) ----------------
// z = b*2 + which.  which==0: q -> xqT (fp16) + xv (bf16).  which==1: x -> xkT + x2 (fp32).
__global__ __launch_bounds__(256, 2) void proj_fused(
    const float* __restrict__ q, const float* __restrict__ x,
    const u16* __restrict__ wq16, const u16* __restrict__ wk16,
    const u16* __restrict__ wv16, const float* __restrict__ bias,
    u16* __restrict__ xqT, u16* __restrict__ xkT,
    u16* __restrict__ xv_bf, float* __restrict__ x2_f32)
{
    __shared__ u16 t_s[64 * 136];     // [n][c] fp16
    int tid = threadIdx.x, lane = tid & 63, wave = tid >> 6;
    int zb = blockIdx.z, b = zb >> 1, which = zb & 1;
    int n0 = blockIdx.x * 64;
    const float* in  = which ? x : q;
    const u16*   wqk = which ? wk16 : wq16;
    u16*         outT = which ? xkT : xqT;
    {
        int r = tid >> 2;             // c within 64-half
        int nc = (tid & 3) * 16;      // n-chunk
        #pragma unroll
        for (int h = 0; h < 2; ++h) {
            const float4* ip4 = (const float4*)(in + ((size_t)b * C2 + h * 64 + r) * NN + n0 + nc);
            #pragma unroll
            for (int jj = 0; jj < 4; ++jj) {
                float4 v = ip4[jj];
                int nbase = nc + jj * 4;
                t_s[(nbase + 0) * 136 + h * 64 + r] = f2h(v.x);
                t_s[(nbase + 1) * 136 + h * 64 + r] = f2h(v.y);
                t_s[(nbase + 2) * 136 + h * 64 + r] = f2h(v.z);
                t_s[(nbase + 3) * 136 + h * 64 + r] = f2h(v.w);
            }
        }
    }
    __syncthreads();
    int nsub = wave & 1, g = wave >> 1;   // g in {0,1}
    int lrow = lane & 31, lk8 = (lane >> 5) * 8;
    const u16* brow = &t_s[(nsub * 32 + lrow) * 136 + lk8];
    f32x16 aq0, aq1, av0, av1, av2, av3;
    #pragma unroll
    for (int r = 0; r < 16; ++r)
        { aq0[r]=0.f; aq1[r]=0.f; av0[r]=0.f; av1[r]=0.f; av2[r]=0.f; av3[r]=0.f; }
    const u16* wq0 = wqk + (size_t)(g * 64 + lrow) * C2 + lk8;
    const u16* wq1 = wqk + (size_t)(g * 64 + 32 + lrow) * C2 + lk8;
    const u16* wv0 = wv16 + (size_t)(g * 128 + lrow) * C2 + lk8;
    const u16* wv1 = wv16 + (size_t)(g * 128 + 32 + lrow) * C2 + lk8;
    const u16* wv2 = wv16 + (size_t)(g * 128 + 64 + lrow) * C2 + lk8;
    const u16* wv3 = wv16 + (size_t)(g * 128 + 96 + lrow) * C2 + lk8;
    #pragma unroll
    for (int kk = 0; kk < 8; ++kk) {
        f16x8 bf = *(const f16x8*)&brow[kk * 16];
        f16x8 q0 = *(const f16x8*)&wq0[kk * 16];
        f16x8 q1 = *(const f16x8*)&wq1[kk * 16];
        aq0 = __builtin_amdgcn_mfma_f32_32x32x16_f16(bf, q0, aq0, 0, 0, 0);
        aq1 = __builtin_amdgcn_mfma_f32_32x32x16_f16(bf, q1, aq1, 0, 0, 0);
        f16x8 v0 = *(const f16x8*)&wv0[kk * 16];
        f16x8 v1 = *(const f16x8*)&wv1[kk * 16];
        f16x8 v2 = *(const f16x8*)&wv2[kk * 16];
        f16x8 v3 = *(const f16x8*)&wv3[kk * 16];
        av0 = __builtin_amdgcn_mfma_f32_32x32x16_f16(v0, bf, av0, 0, 0, 0);
        av1 = __builtin_amdgcn_mfma_f32_32x32x16_f16(v1, bf, av1, 0, 0, 0);
        av2 = __builtin_amdgcn_mfma_f32_32x32x16_f16(v2, bf, av2, 0, 0, 0);
        av3 = __builtin_amdgcn_mfma_f32_32x32x16_f16(v3, bf, av3, 0, 0, 0);
    }
    // qk store: rows n (reg pattern), cols o (lrow)
    #pragma unroll
    for (int r = 0; r < 16; ++r) {
        int ro = (r & 3) + 8 * (r >> 2) + 4 * (lane >> 5);
        size_t row = (size_t)b * NN + n0 + nsub * 32 + ro;
        outT[row * C2 + g * 64 + lrow]      = f2h(aq0[r]);
        outT[row * C2 + g * 64 + 32 + lrow] = f2h(aq1[r]);
    }
    // v store: rows c (reg pattern), cols n (lrow)
    int n = n0 + nsub * 32 + lrow;
    #pragma unroll
    for (int r = 0; r < 16; ++r) {
        int ro = (r & 3) + 8 * (r >> 2) + 4 * (lane >> 5);
        int c0r = g * 128 + ro;
        float w0 = av0[r] + bias[c0r];
        float w1 = av1[r] + bias[c0r + 32];
        float w2 = av2[r] + bias[c0r + 64];
        float w3 = av3[r] + bias[c0r + 96];
        if (which == 0) {
            xv_bf[((size_t)b * CC + c0r) * NN + n]      = f2bf(w0);
            xv_bf[((size_t)b * CC + c0r + 32) * NN + n] = f2bf(w1);
            xv_bf[((size_t)b * CC + c0r + 64) * NN + n] = f2bf(w2);
            xv_bf[((size_t)b * CC + c0r + 96) * NN + n] = f2bf(w3);
        } else {
            x2_f32[((size_t)b * CC + c0r) * NN + n]      = w0;
            x2_f32[((size_t)b * CC + c0r + 32) * NN + n] = w1;
            x2_f32[((size_t)b * CC + c0r + 64) * NN + n] = w2;
            x2_f32[((size_t)b * CC + c0r + 96) * NN + n] = w3;
        }
    }
}

// ---------------- Pass 1: row stats — zero in-loop barriers (r8 proven) ----------------
// xq tile in LDS (loaded once); xk A-fragments read directly from global.
__global__ __launch_bounds__(256, 4) void rowstats_mfma(
    const u16* __restrict__ xqT, const u16* __restrict__ xkT,
    float* __restrict__ rmax, float* __restrict__ rsum)
{
    __shared__ u16 xq_s[64 * 136];
    __shared__ float Mp[4][32];
    __shared__ float Sp[4][32];
    const int tid  = threadIdx.x;
    int flat = blockIdx.x + gridDim.x * blockIdx.y;   // 512
    int xcd = flat & 7, rank = flat >> 3;
    const int b  = xcd * 2 + (rank >> 5);
    const int n0 = (rank & 31) * 64;
    const int lane = tid & 63;
    const int wave = tid >> 6;
    const u16* xqb = xqT + (size_t)b * NN * C2;
    const u16* xkb = xkT + (size_t)b * NN * C2;

    for (int i = tid; i < 64 * 16; i += 256) {
        int r = i >> 4, c8 = i & 15;
        *(uint4*)&xq_s[r * 136 + c8 * 8] =
            *(const uint4*)&xqb[(size_t)(n0 + r) * C2 + c8 * 8];
    }
    __syncthreads();
    const int msub = wave >> 1, nsub = wave & 1;
    const int lrow = lane & 31;
    const int lk8  = (lane >> 5) * 8;
    const u16* brow = &xq_s[(nsub * 32 + lrow) * 136 + lk8];
    float runM = -1e30f, runS = 0.f;

    for (int m0 = 0; m0 < NN; m0 += 64) {
        const u16* arow = xkb + (size_t)(m0 + msub * 32 + lrow) * C2 + lk8;
        f32x16 e;
        #pragma unroll
        for (int r = 0; r < 16; ++r) e[r] = 0.f;
        #pragma unroll
        for (int kk = 0; kk < 8; ++kk) {
            f16x8 a  = *(const f16x8*)&arow[kk * 16];
            f16x8 bb = *(const f16x8*)&brow[kk * 16];
            e = __builtin_amdgcn_mfma_f32_32x32x16_f16(a, bb, e, 0, 0, 0);
        }
        float tm = e[0];
        #pragma unroll
        for (int r = 1; r < 16; ++r) tm = fmaxf(tm, e[r]);
        float newM = fmaxf(runM, tm);
        float sc = __expf(runM - newM);
        float ts = 0.f;
        #pragma unroll
        for (int r = 0; r < 16; ++r) ts += __expf(e[r] - newM);
        runS = runS * sc + ts;
        runM = newM;
    }
    float oM = __shfl_xor(runM, 32, 64);
    float oS = __shfl_xor(runS, 32, 64);
    float M2 = fmaxf(runM, oM);
    float S2 = runS * __expf(runM - M2) + oS * __expf(oM - M2);
    if (lane < 32) { Mp[wave][lane] = M2; Sp[wave][lane] = S2; }
    __syncthreads();
    if (tid < 64) {
        int ns = tid >> 5, li = tid & 31;
        float Ma = Mp[ns][li], Mb = Mp[ns + 2][li];
        float Mf = fmaxf(Ma, Mb);
        float Sf = Sp[ns][li] * __expf(Ma - Mf) + Sp[ns + 2][li] * __expf(Mb - Mf);
        rmax[(size_t)b * NN + n0 + tid] = Mf;
        rsum[(size_t)b * NN + n0 + tid] = Sf;
    }
}

// ---------------- Pass 2: PV + fused dcalc (r6 proven 140 us structure) ----------------
__global__ __launch_bounds__(256) void pv_mfma(
    const u16* __restrict__ xqT, const u16* __restrict__ xkT,
    const u16* __restrict__ xv, const float* __restrict__ rmax,
    const float* __restrict__ rsum, const float* __restrict__ x2,
    u16* __restrict__ dT)
{
    __shared__ u16 xk_s[64 * 136];   // [m][c]  fp16
    __shared__ u16 xq_s[64 * 136];   // [n][c]  fp16
    __shared__ u16 xv_s[256 * 72];   // [c][n]  bf16  (reused as dT transpose buf)
    __shared__ u16 p_s[64 * 72];     // [m][n]  bf16  (reused as s_part)
    __shared__ float M_s[64];        // (reused as sinv)
    __shared__ float Si_s[64];
    const int tid  = threadIdx.x;
    int flat = blockIdx.x + gridDim.x * blockIdx.y;
    int xcd = flat & 7, rank = flat >> 3;
    const int b  = xcd * 2 + (rank >> 5);
    const int m0 = (rank & 31) * 64;
    const int lane = tid & 63;
    const int wave = tid >> 6;
    const u16* xqb = xqT + (size_t)b * NN * C2;
    const u16* xkb = xkT + (size_t)b * NN * C2;
    const u16* xvb = xv + (size_t)b * CC * NN;

    for (int i = tid; i < 64 * 16; i += 256) {
        int r = i >> 4, c8 = i & 15;
        *(uint4*)&xk_s[r * 136 + c8 * 8] =
            *(const uint4*)&xkb[(size_t)(m0 + r) * C2 + c8 * 8];
    }
    f32x16 acc00, acc01, acc10, acc11;
    #pragma unroll
    for (int r = 0; r < 16; ++r)
        { acc00[r] = 0.f; acc01[r] = 0.f; acc10[r] = 0.f; acc11[r] = 0.f; }
    float s_reg = 0.f;
    const int lrow  = lane & 31;
    const int lk8   = (lane >> 5) * 8;
    const int emsub = wave & 1, ensub = wave >> 1;
    const int cbase = wave * 64;
    const int smq   = tid & 63, sq = tid >> 6;

    for (int n0 = 0; n0 < NN; n0 += 64) {
        for (int i = tid; i < 64 * 16; i += 256) {
            int r = i >> 4, c8 = i & 15;
            *(uint4*)&xq_s[r * 136 + c8 * 8] =
                *(const uint4*)&xqb[(size_t)(n0 + r) * C2 + c8 * 8];
        }
        for (int i = tid; i < 256 * 8; i += 256) {
            int c = i >> 3, k8 = i & 7;
            *(uint4*)&xv_s[c * 72 + k8 * 8] =
                *(const uint4*)&xvb[(size_t)c * NN + n0 + k8 * 8];
        }
        if (tid < 64) {
            M_s[tid]  = rmax[(size_t)b * NN + n0 + tid];
            Si_s[tid] = 1.f / rsum[(size_t)b * NN + n0 + tid];
        }
        __syncthreads();
        // energy subtile (32x32) per wave — fp16, same fragments/order as pass 1
        f32x16 e;
        #pragma unroll
        for (int r = 0; r < 16; ++r) e[r] = 0.f;
        {
            const u16* arow = &xk_s[(emsub * 32 + lrow) * 136 + lk8];
            const u16* brow = &xq_s[(ensub * 32 + lrow) * 136 + lk8];
            #pragma unroll
            for (int kk = 0; kk < 8; ++kk) {
                f16x8 a  = *(const f16x8*)&arow[kk * 16];
                f16x8 bb = *(const f16x8*)&brow[kk * 16];
                e = __builtin_amdgcn_mfma_f32_32x32x16_f16(a, bb, e, 0, 0, 0);
            }
        }
        {
            int nl = ensub * 32 + lrow;
            float Mn = M_s[nl], Si = Si_s[nl];
            int mbase = emsub * 32 + 4 * (lane >> 5);
            #pragma unroll
            for (int r = 0; r < 16; ++r) {
                int ml = mbase + (r & 3) + 8 * (r >> 2);
                float p = __expf(e[r] - Mn) * Si;
                p_s[ml * 72 + nl] = f2bf(p);
            }
        }
        __syncthreads();
        // colsum partial (reads the same bf16 P that PV consumes)
        {
            const u16* pr = &p_s[smq * 72 + sq * 16];
            float ss = 0.f;
            #pragma unroll
            for (int j = 0; j < 16; ++j) ss += bf2f(pr[j]);
            s_reg += ss;
        }
        // PV: per wave, c-rows [cbase, cbase+64), both 32-col m-subtiles — bf16 MFMA
        {
            const u16* a0r = &xv_s[(cbase + lrow) * 72 + lk8];
            const u16* a1r = &xv_s[(cbase + 32 + lrow) * 72 + lk8];
            const u16* b0r = &p_s[lrow * 72 + lk8];
            const u16* b1r = &p_s[(32 + lrow) * 72 + lk8];
            #pragma unroll
            for (int kk = 0; kk < 4; ++kk) {
                bf16x8 a0 = *(const bf16x8*)&a0r[kk * 16];
                bf16x8 a1 = *(const bf16x8*)&a1r[kk * 16];
                bf16x8 b0 = *(const bf16x8*)&b0r[kk * 16];
                bf16x8 b1 = *(const bf16x8*)&b1r[kk * 16];
                acc00 = __builtin_amdgcn_mfma_f32_32x32x16_bf16(a0, b0, acc00, 0, 0, 0);
                acc01 = __builtin_amdgcn_mfma_f32_32x32x16_bf16(a0, b1, acc01, 0, 0, 0);
                acc10 = __builtin_amdgcn_mfma_f32_32x32x16_bf16(a1, b0, acc10, 0, 0, 0);
                acc11 = __builtin_amdgcn_mfma_f32_32x32x16_bf16(a1, b1, acc11, 0, 0, 0);
            }
        }
        __syncthreads();
    }
    // ---- fused dcalc epilogue ----
    float* s_part = (float*)p_s;            // p_s dead after loop
    s_part[smq * 4 + sq] = s_reg;
    __syncthreads();
    float* sinv = M_s;                      // M_s dead after loop
    if (tid < 64) {
        float ss = s_part[tid * 4] + s_part[tid * 4 + 1] +
                   s_part[tid * 4 + 2] + s_part[tid * 4 + 3];
        sinv[tid] = 1.f / (1e-9f + ss);
    }
    __syncthreads();
    u16* dts = xv_s;                        // 64 x 264 = 33.8 KB <= 36.8 KB
    const float* x2b = x2 + (size_t)b * CC * NN;
    float si0 = sinv[lrow], si1 = sinv[32 + lrow];
    #pragma unroll
    for (int r = 0; r < 16; ++r) {
        int ro = (r & 3) + 8 * (r >> 2) + 4 * (lane >> 5);
        int c0r = cbase + ro, c1r = cbase + 32 + ro;
        float d00 = x2b[(size_t)c0r * NN + m0 + lrow]      - acc00[r] * si0;
        float d01 = x2b[(size_t)c0r * NN + m0 + 32 + lrow] - acc01[r] * si1;
        float d10 = x2b[(size_t)c1r * NN + m0 + lrow]      - acc10[r] * si0;
        float d11 = x2b[(size_t)c1r * NN + m0 + 32 + lrow] - acc11[r] * si1;
        dts[lrow * 264 + c0r]        = f2h(d00);
        dts[(32 + lrow) * 264 + c0r] = f2h(d01);
        dts[lrow * 264 + c1r]        = f2h(d10);
        dts[(32 + lrow) * 264 + c1r] = f2h(d11);
    }
    __syncthreads();
    u16* op = dT + ((size_t)b * NN + m0) * CC;
    for (int i = tid; i < 64 * 32; i += 256) {
        int r = i >> 5, c8 = i & 31;
        *(uint4*)&op[(size_t)r * CC + c8 * 8] = *(uint4*)&dts[r * 264 + c8 * 8];
    }
}

// ---------------- final (MFMA): out = relu(BN(Wt·d + bt)) + x2 ----------------
__global__ __launch_bounds__(256) void final_mfma(
    const u16* __restrict__ dT, const u16* __restrict__ wt16,
    const float* __restrict__ bt, const float* __restrict__ gamma,
    const float* __restrict__ beta, const float* __restrict__ rmean,
    const float* __restrict__ rvar, const float* __restrict__ x2,
    float* __restrict__ out)
{
    __shared__ u16 b_s[64 * 264];
    __shared__ float inv_s[128], add_s[128];
    int tid = threadIdx.x, lane = tid & 63, wave = tid >> 6;
    int n0 = blockIdx.x * 64, o0 = blockIdx.y * 128, b = blockIdx.z;
    for (int i = tid; i < 64 * 32; i += 256) {
        int r = i >> 5, c8 = i & 31;
        *(uint4*)&b_s[r * 264 + c8 * 8] =
            *(const uint4*)&dT[((size_t)b * NN + n0 + r) * CC + c8 * 8];
    }
    if (tid < 128) {
        int o = o0 + tid;
        float iv = gamma[o] * rsqrtf(rvar[o] + 1e-5f);
        inv_s[tid] = iv;
        add_s[tid] = bt[o] * iv + beta[o] - rmean[o] * iv;
    }
    __syncthreads();
    int oh = wave >> 1, nsub = wave & 1;
    int lrow = lane & 31, lk8 = (lane >> 5) * 8;
    f32x16 acc0, acc1;
    #pragma unroll
    for (int r = 0; r < 16; ++r) { acc0[r] = 0.f; acc1[r] = 0.f; }
    const u16* brow = &b_s[(nsub * 32 + lrow) * 264 + lk8];
    const u16* a0p = wt16 + (size_t)(o0 + oh * 64 + lrow) * CC + lk8;
    const u16* a1p = wt16 + (size_t)(o0 + oh * 64 + 32 + lrow) * CC + lk8;
    #pragma unroll
    for (int kk = 0; kk < 16; ++kk) {
        f16x8 bb = *(const f16x8*)&brow[kk * 16];
        f16x8 a0 = *(const f16x8*)&a0p[kk * 16];
        f16x8 a1 = *(const f16x8*)&a1p[kk * 16];
        acc0 = __builtin_amdgcn_mfma_f32_32x32x16_f16(a0, bb, acc0, 0, 0, 0);
        acc1 = __builtin_amdgcn_mfma_f32_32x32x16_f16(a1, bb, acc1, 0, 0, 0);
    }
    int n = n0 + nsub * 32 + (lane & 31);
    #pragma unroll
    for (int r = 0; r < 16; ++r) {
        int ro = (r & 3) + 8 * (r >> 2) + 4 * (lane >> 5);
        int ol0 = oh * 64 + ro, ol1 = ol0 + 32;
        float t0 = acc0[r] * inv_s[ol0] + add_s[ol0];
        float t1 = acc1[r] * inv_s[ol1] + add_s[ol1];
        size_t i0 = ((size_t)b * CC + o0 + ol0) * NN + n;
        size_t i1 = ((size_t)b * CC + o0 + ol1) * NN + n;
        out[i0] = fmaxf(t0, 0.f) + x2[i0];
        out[i1] = fmaxf(t1, 0.f) + x2[i1];
    }
}

extern "C" void kernel_launch(void* const* d_in, const int* in_sizes, int n_in,
                              void* d_out, int out_size, void* d_ws, size_t ws_size,
                              hipStream_t stream)
{
    const float* q     = (const float*)d_in[0];
    const float* x     = (const float*)d_in[1];
    const float* Wq    = (const float*)d_in[2];
    const float* Wk    = (const float*)d_in[3];
    const float* Wv    = (const float*)d_in[4];
    const float* bv    = (const float*)d_in[5];
    const float* Wt    = (const float*)d_in[6];
    const float* bt    = (const float*)d_in[7];
    const float* gamma = (const float*)d_in[8];
    const float* beta  = (const float*)d_in[9];
    const float* rmean = (const float*)d_in[10];
    const float* rvar  = (const float*)d_in[11];
    float* out = (float*)d_out;
    float* ws  = (float*)d_ws;

    float* x2   = ws + OFF_X2;
    u16*   u1   = (u16*)(ws + OFF_U16);
    u16*   xqT  = u1 + UOFF_XQT;
    u16*   xkT  = u1 + UOFF_XKT;
    u16*   xv   = u1 + UOFF_XV;
    float* rmax = ws + OFF_RMAX;
    float* rsum = ws + OFF_RSUM;
    u16*   dT   = (u16*)(ws + OFF_T16);
    u16*   w16  = (u16*)(ws + OFF_W16);

    dim3 blk(256);
    prep_w<<<dim3(512), blk, 0, stream>>>(Wq, Wk, Wv, Wt, w16);
    proj_fused<<<dim3(NN/64, 1, 2*BB), blk, 0, stream>>>(
        q, x, w16 + WOFF_WQ, w16 + WOFF_WK, w16 + WOFF_WV, bv,
        xqT, xkT, xv, x2);
    rowstats_mfma<<<dim3(NN/64, BB), blk, 0, stream>>>(xqT, xkT, rmax, rsum);
    pv_mfma<<<dim3(NN/64, BB), blk, 0, stream>>>(xqT, xkT, xv, rmax, rsum, x2, dT);
    final_mfma<<<dim3(NN/64, 2, BB), blk, 0, stream>>>(dT, w16 + WOFF_WT, bt, gamma,
                                                       beta, rmean, rvar, x2, out);
}

// Round 12
// 324.872 us; speedup vs baseline: 1.2721x; 1.0331x over previous
//
#include <hip/hip_runtime.h>
#include <hip/hip_bf16.h>
#include <math.h>

#define BB 16
#define CC 256
#define C2 128
#define NN 2048

typedef __attribute__((ext_vector_type(8))) _Float16 f16x8;
typedef __attribute__((ext_vector_type(8))) short bf16x8;
typedef __attribute__((ext_vector_type(16))) float f32x16;
typedef unsigned short u16;

// ---- workspace layout (float offsets) ----
#define OFF_X2   ((size_t)0)           // x2 fp32 [B][C][N]
#define OFF_U16  ((size_t)16777216)    // u16 region 1: XQT | XKT | XV
#define UOFF_XQT ((size_t)0)           // fp16 [B][N][C2]
#define UOFF_XKT ((size_t)4194304)     // fp16 [B][N][C2]
#define UOFF_XV  ((size_t)8388608)     // bf16 [B][C][N]
#define OFF_RMAX ((size_t)25165824)
#define OFF_RSUM ((size_t)25198592)
#define OFF_T16  ((size_t)25264128)    // u16 region 2: dT fp16 [B][N][CC]
#define OFF_W16  ((size_t)29458432)    // u16: Wq16|Wk16|Wv16|Wt16
#define WOFF_WQ  ((size_t)0)
#define WOFF_WK  ((size_t)16384)
#define WOFF_WV  ((size_t)32768)
#define WOFF_WT  ((size_t)65536)

__device__ __forceinline__ u16 f2h(float f) {
    union { _Float16 h; u16 u; } v; v.h = (_Float16)f;
    return v.u;
}
__device__ __forceinline__ u16 f2bf(float f) {
    union { float f; unsigned u; } v; v.f = f;
    return (u16)((v.u + 0x7fffu + ((v.u >> 16) & 1u)) >> 16);
}
__device__ __forceinline__ float bf2f(u16 h) {
    union { unsigned u; float f; } v; v.u = ((unsigned)h) << 16;
    return v.f;
}

// ---------------- prep: weights -> fp16 ----------------
__global__ __launch_bounds__(256) void prep_w(
    const float* __restrict__ Wq, const float* __restrict__ Wk,
    const float* __restrict__ Wv, const float* __restrict__ Wt,
    u16* __restrict__ w16)
{
    int i = blockIdx.x * 256 + threadIdx.x;   // 131072 total
    float v;
    if (i < 16384)      v = Wq[i];
    else if (i < 32768) v = Wk[i - 16384];
    else if (i < 65536) v = Wv[i - 32768];
    else                v = Wt[i - 65536];
    w16[i] = f2h(v);
}

// ---------------- fused projection (both inputs in ONE launch) ----------------
__global__ __launch_bounds__(256, 2) void proj_fused(
    const float* __restrict__ q, const float* __restrict__ x,
    const u16* __restrict__ wq16, const u16* __restrict__ wk16,
    const u16* __restrict__ wv16, const float* __restrict__ bias,
    u16* __restrict__ xqT, u16* __restrict__ xkT,
    u16* __restrict__ xv_bf, float* __restrict__ x2_f32)
{
    __shared__ u16 t_s[64 * 136];     // [n][c] fp16
    int tid = threadIdx.x, lane = tid & 63, wave = tid >> 6;
    int zb = blockIdx.z, b = zb >> 1, which = zb & 1;
    int n0 = blockIdx.x * 64;
    const float* in  = which ? x : q;
    const u16*   wqk = which ? wk16 : wq16;
    u16*         outT = which ? xkT : xqT;
    {
        int r = tid >> 2;             // c within 64-half
        int nc = (tid & 3) * 16;      // n-chunk
        #pragma unroll
        for (int h = 0; h < 2; ++h) {
            const float4* ip4 = (const float4*)(in + ((size_t)b * C2 + h * 64 + r) * NN + n0 + nc);
            #pragma unroll
            for (int jj = 0; jj < 4; ++jj) {
                float4 v = ip4[jj];
                int nbase = nc + jj * 4;
                t_s[(nbase + 0) * 136 + h * 64 + r] = f2h(v.x);
                t_s[(nbase + 1) * 136 + h * 64 + r] = f2h(v.y);
                t_s[(nbase + 2) * 136 + h * 64 + r] = f2h(v.z);
                t_s[(nbase + 3) * 136 + h * 64 + r] = f2h(v.w);
            }
        }
    }
    __syncthreads();
    int nsub = wave & 1, g = wave >> 1;   // g in {0,1}
    int lrow = lane & 31, lk8 = (lane >> 5) * 8;
    const u16* brow = &t_s[(nsub * 32 + lrow) * 136 + lk8];
    f32x16 aq0, aq1, av0, av1, av2, av3;
    #pragma unroll
    for (int r = 0; r < 16; ++r)
        { aq0[r]=0.f; aq1[r]=0.f; av0[r]=0.f; av1[r]=0.f; av2[r]=0.f; av3[r]=0.f; }
    const u16* wq0 = wqk + (size_t)(g * 64 + lrow) * C2 + lk8;
    const u16* wq1 = wqk + (size_t)(g * 64 + 32 + lrow) * C2 + lk8;
    const u16* wv0 = wv16 + (size_t)(g * 128 + lrow) * C2 + lk8;
    const u16* wv1 = wv16 + (size_t)(g * 128 + 32 + lrow) * C2 + lk8;
    const u16* wv2 = wv16 + (size_t)(g * 128 + 64 + lrow) * C2 + lk8;
    const u16* wv3 = wv16 + (size_t)(g * 128 + 96 + lrow) * C2 + lk8;
    #pragma unroll
    for (int kk = 0; kk < 8; ++kk) {
        f16x8 bf = *(const f16x8*)&brow[kk * 16];
        f16x8 q0 = *(const f16x8*)&wq0[kk * 16];
        f16x8 q1 = *(const f16x8*)&wq1[kk * 16];
        aq0 = __builtin_amdgcn_mfma_f32_32x32x16_f16(bf, q0, aq0, 0, 0, 0);
        aq1 = __builtin_amdgcn_mfma_f32_32x32x16_f16(bf, q1, aq1, 0, 0, 0);
        f16x8 v0 = *(const f16x8*)&wv0[kk * 16];
        f16x8 v1 = *(const f16x8*)&wv1[kk * 16];
        f16x8 v2 = *(const f16x8*)&wv2[kk * 16];
        f16x8 v3 = *(const f16x8*)&wv3[kk * 16];
        av0 = __builtin_amdgcn_mfma_f32_32x32x16_f16(v0, bf, av0, 0, 0, 0);
        av1 = __builtin_amdgcn_mfma_f32_32x32x16_f16(v1, bf, av1, 0, 0, 0);
        av2 = __builtin_amdgcn_mfma_f32_32x32x16_f16(v2, bf, av2, 0, 0, 0);
        av3 = __builtin_amdgcn_mfma_f32_32x32x16_f16(v3, bf, av3, 0, 0, 0);
    }
    #pragma unroll
    for (int r = 0; r < 16; ++r) {
        int ro = (r & 3) + 8 * (r >> 2) + 4 * (lane >> 5);
        size_t row = (size_t)b * NN + n0 + nsub * 32 + ro;
        outT[row * C2 + g * 64 + lrow]      = f2h(aq0[r]);
        outT[row * C2 + g * 64 + 32 + lrow] = f2h(aq1[r]);
    }
    int n = n0 + nsub * 32 + lrow;
    #pragma unroll
    for (int r = 0; r < 16; ++r) {
        int ro = (r & 3) + 8 * (r >> 2) + 4 * (lane >> 5);
        int c0r = g * 128 + ro;
        float w0 = av0[r] + bias[c0r];
        float w1 = av1[r] + bias[c0r + 32];
        float w2 = av2[r] + bias[c0r + 64];
        float w3 = av3[r] + bias[c0r + 96];
        if (which == 0) {
            xv_bf[((size_t)b * CC + c0r) * NN + n]      = f2bf(w0);
            xv_bf[((size_t)b * CC + c0r + 32) * NN + n] = f2bf(w1);
            xv_bf[((size_t)b * CC + c0r + 64) * NN + n] = f2bf(w2);
            xv_bf[((size_t)b * CC + c0r + 96) * NN + n] = f2bf(w3);
        } else {
            x2_f32[((size_t)b * CC + c0r) * NN + n]      = w0;
            x2_f32[((size_t)b * CC + c0r + 32) * NN + n] = w1;
            x2_f32[((size_t)b * CC + c0r + 64) * NN + n] = w2;
            x2_f32[((size_t)b * CC + c0r + 96) * NN + n] = w3;
        }
    }
}

// ---------------- Pass 1: row stats — m-step 128/iter, dual e-chains, zero in-loop barriers ----------------
__global__ __launch_bounds__(256, 4) void rowstats_mfma(
    const u16* __restrict__ xqT, const u16* __restrict__ xkT,
    float* __restrict__ rmax, float* __restrict__ rsum)
{
    __shared__ u16 xq_s[64 * 136];
    __shared__ float Mp[4][32];
    __shared__ float Sp[4][32];
    const int tid  = threadIdx.x;
    int flat = blockIdx.x + gridDim.x * blockIdx.y;   // 512
    int xcd = flat & 7, rank = flat >> 3;
    const int b  = xcd * 2 + (rank >> 5);
    const int n0 = (rank & 31) * 64;
    const int lane = tid & 63;
    const int wave = tid >> 6;
    const u16* xqb = xqT + (size_t)b * NN * C2;
    const u16* xkb = xkT + (size_t)b * NN * C2;

    for (int i = tid; i < 64 * 16; i += 256) {
        int r = i >> 4, c8 = i & 15;
        *(uint4*)&xq_s[r * 136 + c8 * 8] =
            *(const uint4*)&xqb[(size_t)(n0 + r) * C2 + c8 * 8];
    }
    __syncthreads();
    const int mpair = wave >> 1, nsub = wave & 1;
    const int lrow = lane & 31;
    const int lk8  = (lane >> 5) * 8;
    const u16* brow = &xq_s[(nsub * 32 + lrow) * 136 + lk8];
    float runM = -1e30f, runS = 0.f;

    for (int m0 = 0; m0 < NN; m0 += 128) {
        const u16* a0row = xkb + (size_t)(m0 + mpair * 64 + lrow) * C2 + lk8;
        const u16* a1row = xkb + (size_t)(m0 + mpair * 64 + 32 + lrow) * C2 + lk8;
        f32x16 e0, e1;
        #pragma unroll
        for (int r = 0; r < 16; ++r) { e0[r] = 0.f; e1[r] = 0.f; }
        #pragma unroll
        for (int kk = 0; kk < 8; ++kk) {
            f16x8 bb = *(const f16x8*)&brow[kk * 16];
            f16x8 a0 = *(const f16x8*)&a0row[kk * 16];
            f16x8 a1 = *(const f16x8*)&a1row[kk * 16];
            e0 = __builtin_amdgcn_mfma_f32_32x32x16_f16(a0, bb, e0, 0, 0, 0);
            e1 = __builtin_amdgcn_mfma_f32_32x32x16_f16(a1, bb, e1, 0, 0, 0);
        }
        float tm = fmaxf(e0[0], e1[0]);
        #pragma unroll
        for (int r = 1; r < 16; ++r) tm = fmaxf(tm, fmaxf(e0[r], e1[r]));
        float newM = fmaxf(runM, tm);
        float sc = __expf(runM - newM);
        float ts = 0.f;
        #pragma unroll
        for (int r = 0; r < 16; ++r) ts += __expf(e0[r] - newM) + __expf(e1[r] - newM);
        runS = runS * sc + ts;
        runM = newM;
    }
    float oM = __shfl_xor(runM, 32, 64);
    float oS = __shfl_xor(runS, 32, 64);
    float M2 = fmaxf(runM, oM);
    float S2 = runS * __expf(runM - M2) + oS * __expf(oM - M2);
    if (lane < 32) { Mp[wave][lane] = M2; Sp[wave][lane] = S2; }
    __syncthreads();
    if (tid < 64) {
        int ns = tid >> 5, li = tid & 31;
        float Ma = Mp[ns][li], Mb = Mp[ns + 2][li];
        float Mf = fmaxf(Ma, Mb);
        float Sf = Sp[ns][li] * __expf(Ma - Mf) + Sp[ns + 2][li] * __expf(Mb - Mf);
        rmax[(size_t)b * NN + n0 + tid] = Mf;
        rsum[(size_t)b * NN + n0 + tid] = Sf;
    }
}

// ---------------- Pass 2: PV + fused dcalc — n-step 128 (16 iters), xv direct-global ----------------
__global__ __launch_bounds__(256) void pv_mfma(
    const u16* __restrict__ xqT, const u16* __restrict__ xkT,
    const u16* __restrict__ xv, const float* __restrict__ rmax,
    const float* __restrict__ rsum, const float* __restrict__ x2,
    u16* __restrict__ dT)
{
    __shared__ u16 smem[34816];      // xk_s[0,8704) | xq_s[8704,26112) | p_s[26112,34816)
    __shared__ float M_s[128];
    __shared__ float Si_s[128];
    u16* xk_s = smem;                // [64][136] fp16  (m rows)
    u16* xq_s = smem + 8704;         // [128][136] fp16 (n rows)
    u16* p_s  = smem + 26112;        // [64][136] bf16  ([m][n], n-step 128)
    const int tid  = threadIdx.x;
    int flat = blockIdx.x + gridDim.x * blockIdx.y;
    int xcd = flat & 7, rank = flat >> 3;
    const int b  = xcd * 2 + (rank >> 5);
    const int m0 = (rank & 31) * 64;
    const int lane = tid & 63;
    const int wave = tid >> 6;
    const u16* xqb = xqT + (size_t)b * NN * C2;
    const u16* xkb = xkT + (size_t)b * NN * C2;
    const u16* xvb = xv + (size_t)b * CC * NN;

    for (int i = tid; i < 64 * 16; i += 256) {
        int r = i >> 4, c8 = i & 15;
        *(uint4*)&xk_s[r * 136 + c8 * 8] =
            *(const uint4*)&xkb[(size_t)(m0 + r) * C2 + c8 * 8];
    }
    f32x16 acc00, acc01, acc10, acc11;
    #pragma unroll
    for (int r = 0; r < 16; ++r)
        { acc00[r] = 0.f; acc01[r] = 0.f; acc10[r] = 0.f; acc11[r] = 0.f; }
    float s_reg = 0.f;
    const int lrow  = lane & 31;
    const int lk8   = (lane >> 5) * 8;
    const int emsub = wave & 1;      // energy m-subtile
    const int enq   = wave >> 1;     // energy n-pair (2 of 4 n-subtiles)
    const int cbase = wave * 64;
    const int cs_m  = tid & 63, cs_q = tid >> 6;   // colsum: m, 32-n quarter
    const int mbase = emsub * 32 + 4 * (lane >> 5);
    const int nl0   = enq * 64 + lrow, nl1 = nl0 + 32;

    for (int n0 = 0; n0 < NN; n0 += 128) {
        // stage xq (128 rows) + stats
        for (int i = tid; i < 128 * 16; i += 256) {
            int r = i >> 4, c8 = i & 15;
            *(uint4*)&xq_s[r * 136 + c8 * 8] =
                *(const uint4*)&xqb[(size_t)(n0 + r) * C2 + c8 * 8];
        }
        if (tid < 128) {
            M_s[tid]  = rmax[(size_t)b * NN + n0 + tid];
            Si_s[tid] = 1.f / rsum[(size_t)b * NN + n0 + tid];
        }
        __syncthreads();   // A: xq_s, M_s ready
        // energy: per wave 2 subtiles (32m x 32n), shared A, dual chains
        f32x16 e0, e1;
        #pragma unroll
        for (int r = 0; r < 16; ++r) { e0[r] = 0.f; e1[r] = 0.f; }
        {
            const u16* arow  = &xk_s[(emsub * 32 + lrow) * 136 + lk8];
            const u16* brow0 = &xq_s[nl0 * 136 + lk8];
            const u16* brow1 = &xq_s[nl1 * 136 + lk8];
            #pragma unroll
            for (int kk = 0; kk < 8; ++kk) {
                f16x8 a  = *(const f16x8*)&arow[kk * 16];
                f16x8 b0 = *(const f16x8*)&brow0[kk * 16];
                f16x8 b1 = *(const f16x8*)&brow1[kk * 16];
                e0 = __builtin_amdgcn_mfma_f32_32x32x16_f16(a, b0, e0, 0, 0, 0);
                e1 = __builtin_amdgcn_mfma_f32_32x32x16_f16(a, b1, e1, 0, 0, 0);
            }
        }
        {
            float Mn0 = M_s[nl0], Si0 = Si_s[nl0];
            float Mn1 = M_s[nl1], Si1 = Si_s[nl1];
            #pragma unroll
            for (int r = 0; r < 16; ++r) {
                int ml = mbase + (r & 3) + 8 * (r >> 2);
                p_s[ml * 136 + nl0] = f2bf(__expf(e0[r] - Mn0) * Si0);
                p_s[ml * 136 + nl1] = f2bf(__expf(e1[r] - Mn1) * Si1);
            }
        }
        __syncthreads();   // B: p_s ready
        // colsum partial: thread sums 32 n (2 x b128) for its m
        {
            const uint4* pr = (const uint4*)&p_s[cs_m * 136 + cs_q * 32];
            uint4 v0 = pr[0], v1 = pr[1], v2 = pr[2], v3 = pr[3];
            unsigned wsv[16] = {v0.x, v0.y, v0.z, v0.w, v1.x, v1.y, v1.z, v1.w,
                                v2.x, v2.y, v2.z, v2.w, v3.x, v3.y, v3.z, v3.w};
            float ss = 0.f;
            #pragma unroll
            for (int j = 0; j < 16; ++j) {
                union { unsigned u; float f; } lo, hi;
                lo.u = wsv[j] << 16;
                hi.u = wsv[j] & 0xffff0000u;
                ss += lo.f + hi.f;
            }
            s_reg += ss;
        }
        // PV: A = xv direct from global (bf16 [c][n]), B = p_s; K = 128
        {
            const u16* a0g = xvb + (size_t)(cbase + lrow) * NN + n0 + lk8;
            const u16* a1g = xvb + (size_t)(cbase + 32 + lrow) * NN + n0 + lk8;
            const u16* br0 = &p_s[lrow * 136 + lk8];
            const u16* br1 = &p_s[(32 + lrow) * 136 + lk8];
            #pragma unroll
            for (int kk = 0; kk < 8; ++kk) {
                bf16x8 a0 = *(const bf16x8*)&a0g[kk * 16];
                bf16x8 a1 = *(const bf16x8*)&a1g[kk * 16];
                bf16x8 b0 = *(const bf16x8*)&br0[kk * 16];
                bf16x8 b1 = *(const bf16x8*)&br1[kk * 16];
                acc00 = __builtin_amdgcn_mfma_f32_32x32x16_bf16(a0, b0, acc00, 0, 0, 0);
                acc01 = __builtin_amdgcn_mfma_f32_32x32x16_bf16(a0, b1, acc01, 0, 0, 0);
                acc10 = __builtin_amdgcn_mfma_f32_32x32x16_bf16(a1, b0, acc10, 0, 0, 0);
                acc11 = __builtin_amdgcn_mfma_f32_32x32x16_bf16(a1, b1, acc11, 0, 0, 0);
            }
        }
        __syncthreads();   // C: p_s/xq_s reads done before next iter's writes
    }
    // ---- fused dcalc epilogue ----
    float* s_part = (float*)&smem[26112];   // [64][4] floats (p_s region, dead)
    s_part[cs_m * 4 + cs_q] = s_reg;
    __syncthreads();
    float* sinv = (float*)&smem[27136];     // 64 floats
    if (tid < 64) {
        float ss = s_part[tid * 4] + s_part[tid * 4 + 1] +
                   s_part[tid * 4 + 2] + s_part[tid * 4 + 3];
        sinv[tid] = 1.f / (1e-9f + ss);
    }
    __syncthreads();
    u16* dts = smem + 8704;                 // [64][264] u16 = 16896 <= 17408 (xq_s region)
    const float* x2b = x2 + (size_t)b * CC * NN;
    float si0 = sinv[lrow], si1 = sinv[32 + lrow];
    #pragma unroll
    for (int r = 0; r < 16; ++r) {
        int ro = (r & 3) + 8 * (r >> 2) + 4 * (lane >> 5);
        int c0r = cbase + ro, c1r = cbase + 32 + ro;
        float d00 = x2b[(size_t)c0r * NN + m0 + lrow]      - acc00[r] * si0;
        float d01 = x2b[(size_t)c0r * NN + m0 + 32 + lrow] - acc01[r] * si1;
        float d10 = x2b[(size_t)c1r * NN + m0 + lrow]      - acc10[r] * si0;
        float d11 = x2b[(size_t)c1r * NN + m0 + 32 + lrow] - acc11[r] * si1;
        dts[lrow * 264 + c0r]        = f2h(d00);
        dts[(32 + lrow) * 264 + c0r] = f2h(d01);
        dts[lrow * 264 + c1r]        = f2h(d10);
        dts[(32 + lrow) * 264 + c1r] = f2h(d11);
    }
    __syncthreads();
    u16* op = dT + ((size_t)b * NN + m0) * CC;
    for (int i = tid; i < 64 * 32; i += 256) {
        int r = i >> 5, c8 = i & 31;
        *(uint4*)&op[(size_t)r * CC + c8 * 8] = *(uint4*)&dts[r * 264 + c8 * 8];
    }
}

// ---------------- final (MFMA): out = relu(BN(Wt·d + bt)) + x2 ----------------
__global__ __launch_bounds__(256) void final_mfma(
    const u16* __restrict__ dT, const u16* __restrict__ wt16,
    const float* __restrict__ bt, const float* __restrict__ gamma,
    const float* __restrict__ beta, const float* __restrict__ rmean,
    const float* __restrict__ rvar, const float* __restrict__ x2,
    float* __restrict__ out)
{
    __shared__ u16 b_s[64 * 264];
    __shared__ float inv_s[128], add_s[128];
    int tid = threadIdx.x, lane = tid & 63, wave = tid >> 6;
    int n0 = blockIdx.x * 64, o0 = blockIdx.y * 128, b = blockIdx.z;
    for (int i = tid; i < 64 * 32; i += 256) {
        int r = i >> 5, c8 = i & 31;
        *(uint4*)&b_s[r * 264 + c8 * 8] =
            *(const uint4*)&dT[((size_t)b * NN + n0 + r) * CC + c8 * 8];
    }
    if (tid < 128) {
        int o = o0 + tid;
        float iv = gamma[o] * rsqrtf(rvar[o] + 1e-5f);
        inv_s[tid] = iv;
        add_s[tid] = bt[o] * iv + beta[o] - rmean[o] * iv;
    }
    __syncthreads();
    int oh = wave >> 1, nsub = wave & 1;
    int lrow = lane & 31, lk8 = (lane >> 5) * 8;
    f32x16 acc0, acc1;
    #pragma unroll
    for (int r = 0; r < 16; ++r) { acc0[r] = 0.f; acc1[r] = 0.f; }
    const u16* brow = &b_s[(nsub * 32 + lrow) * 264 + lk8];
    const u16* a0p = wt16 + (size_t)(o0 + oh * 64 + lrow) * CC + lk8;
    const u16* a1p = wt16 + (size_t)(o0 + oh * 64 + 32 + lrow) * CC + lk8;
    #pragma unroll
    for (int kk = 0; kk < 16; ++kk) {
        f16x8 bb = *(const f16x8*)&brow[kk * 16];
        f16x8 a0 = *(const f16x8*)&a0p[kk * 16];
        f16x8 a1 = *(const f16x8*)&a1p[kk * 16];
        acc0 = __builtin_amdgcn_mfma_f32_32x32x16_f16(a0, bb, acc0, 0, 0, 0);
        acc1 = __builtin_amdgcn_mfma_f32_32x32x16_f16(a1, bb, acc1, 0, 0, 0);
    }
    int n = n0 + nsub * 32 + (lane & 31);
    #pragma unroll
    for (int r = 0; r < 16; ++r) {
        int ro = (r & 3) + 8 * (r >> 2) + 4 * (lane >> 5);
        int ol0 = oh * 64 + ro, ol1 = ol0 + 32;
        float t0 = acc0[r] * inv_s[ol0] + add_s[ol0];
        float t1 = acc1[r] * inv_s[ol1] + add_s[ol1];
        size_t i0 = ((size_t)b * CC + o0 + ol0) * NN + n;
        size_t i1 = ((size_t)b * CC + o0 + ol1) * NN + n;
        out[i0] = fmaxf(t0, 0.f) + x2[i0];
        out[i1] = fmaxf(t1, 0.f) + x2[i1];
    }
}

extern "C" void kernel_launch(void* const* d_in, const int* in_sizes, int n_in,
                              void* d_out, int out_size, void* d_ws, size_t ws_size,
                              hipStream_t stream)
{
    const float* q     = (const float*)d_in[0];
    const float* x     = (const float*)d_in[1];
    const float* Wq    = (const float*)d_in[2];
    const float* Wk    = (const float*)d_in[3];
    const float* Wv    = (const float*)d_in[4];
    const float* bv    = (const float*)d_in[5];
    const float* Wt    = (const float*)d_in[6];
    const float* bt    = (const float*)d_in[7];
    const float* gamma = (const float*)d_in[8];
    const float* beta  = (const float*)d_in[9];
    const float* rmean = (const float*)d_in[10];
    const float* rvar  = (const float*)d_in[11];
    float* out = (float*)d_out;
    float* ws  = (float*)d_ws;

    float* x2   = ws + OFF_X2;
    u16*   u1   = (u16*)(ws + OFF_U16);
    u16*   xqT  = u1 + UOFF_XQT;
    u16*   xkT  = u1 + UOFF_XKT;
    u16*   xv   = u1 + UOFF_XV;
    float* rmax = ws + OFF_RMAX;
    float* rsum = ws + OFF_RSUM;
    u16*   dT   = (u16*)(ws + OFF_T16);
    u16*   w16  = (u16*)(ws + OFF_W16);

    dim3 blk(256);
    prep_w<<<dim3(512), blk, 0, stream>>>(Wq, Wk, Wv, Wt, w16);
    proj_fused<<<dim3(NN/64, 1, 2*BB), blk, 0, stream>>>(
        q, x, w16 + WOFF_WQ, w16 + WOFF_WK, w16 + WOFF_WV, bv,
        xqT, xkT, xv, x2);
    rowstats_mfma<<<dim3(NN/64, BB), blk, 0, stream>>>(xqT, xkT, rmax, rsum);
    pv_mfma<<<dim3(NN/64, BB), blk, 0, stream>>>(xqT, xkT, xv, rmax, rsum, x2, dT);
    final_mfma<<<dim3(NN/64, 2, BB), blk, 0, stream>>>(dT, w16 + WOFF_WT, bt, gamma,
                                                       beta, rmean, rvar, x2, out);
}